// Round 10
// baseline (57.723 us; speedup 1.0000x reference)
//
#include <hip/hip_runtime.h>

namespace {

constexpr int S_LEN = 2048;
constexpr int H_N   = 8;
constexpr int D_DIM = 64;
constexpr int N_DIM = 32;
constexpr int TW    = 16;             // timesteps per chunk
constexpr int NKC   = S_LEN / TW;     // 128 chunks per (b,h)
constexpr float NLOG2E = -1.4426950408889634f;

// ws:
//   sdtb: [kc][ch]          128*1024 floats  (0.5 MB)  — sum of dt over chunk
//   bagg: [kc][n][ch]       128*32*1024      (16.8 MB) — chunk b-aggregate
//   pref: [kc][n][ch]       128*32*1024      (16.8 MB) — state entering chunk
// Thread mapping (K1/K3): block = bh*64 + kcg (256 thr = 4 waves = 2 wave-pairs).
//   wave-pair p = w>>1 owns chunk kc = kcg*2+p ; dh = w&1.
//   lane: dlow = lane&31, nh = lane>>5 ; d = dh*32+dlow ; n in [nh*16, nh*16+16).
// dt/u reads: 128 B per half-wave (broadcast across nh) ; B/C reads: 16 B quads
// broadcast per half-wave. All coalesced / cache-friendly; no LDS, no barriers.

__global__ __launch_bounds__(256, 4) void ssm_k1(
    const float* __restrict__ dtp, const float* __restrict__ up,
    const float* __restrict__ Ap,  const float* __restrict__ Bp,
    float* __restrict__ sdtb, float* __restrict__ bagg)
{
    const int tid  = threadIdx.x;
    const int w    = tid >> 6;
    const int lane = tid & 63;
    const int pp   = w >> 1;
    const int dh   = w & 1;
    const int dlow = lane & 31;
    const int nh   = lane >> 5;
    const int bh   = blockIdx.x >> 6;
    const int kcg  = blockIdx.x & 63;
    const int kc   = kcg * 2 + pp;
    const int b = bh >> 3, hh = bh & 7;
    const int d  = dh * 32 + dlow;
    const int n0 = nh * 16;
    const int ch = bh * 64 + d;

    float Aneg[16];
    {
        const float* Arow = Ap + (hh * D_DIM + d) * N_DIM + n0;
#pragma unroll
        for (int j = 0; j < 4; ++j) {
            float4 a4 = *(const float4*)(Arow + j * 4);
            Aneg[4*j+0] = NLOG2E * a4.x; Aneg[4*j+1] = NLOG2E * a4.y;
            Aneg[4*j+2] = NLOG2E * a4.z; Aneg[4*j+3] = NLOG2E * a4.w;
        }
    }

    const int base_ud = b * (S_LEN * 512) + hh * 64 + d;
    const int base_bc = b * (S_LEN * 256) + hh * 32 + n0;
    const int s0 = kc * TW;

    float bA[16];
#pragma unroll
    for (int j = 0; j < 16; ++j) bA[j] = 0.0f;
    float sdt = 0.0f;

#pragma unroll 4
    for (int t = 0; t < TW; ++t) {
        const int s = s0 + t;
        const float dtv = dtp[base_ud + s * 512];
        const float uv  = up [base_ud + s * 512];
        const float kk  = dtv * uv;
        sdt += dtv;
        const float4* B4 = reinterpret_cast<const float4*>(Bp + base_bc + s * 256);
#pragma unroll
        for (int j = 0; j < 4; ++j) {
            const float4 Bv = B4[j];
#pragma unroll
            for (int q = 0; q < 4; ++q) {
                const int jn = j * 4 + q;
                const float bq = (q == 0) ? Bv.x : (q == 1) ? Bv.y : (q == 2) ? Bv.z : Bv.w;
                const float e = __builtin_amdgcn_exp2f(dtv * Aneg[jn]);
                bA[jn] = fmaf(e, bA[jn], kk * bq);
            }
        }
    }

    if (nh == 0) sdtb[kc * 1024 + ch] = sdt;
    const int ab = kc * 32768 + ch;
#pragma unroll
    for (int j = 0; j < 16; ++j)
        bagg[ab + (n0 + j) * 1024] = bA[j];
}

__global__ __launch_bounds__(256) void ssm_k2(
    const float* __restrict__ sdtb, const float* __restrict__ bagg,
    const float* __restrict__ Ap,   float* __restrict__ pref)
{
    const int T  = blockIdx.x * 256 + threadIdx.x;   // 32768 threads = (n, ch)
    const int ch = T & 1023;
    const int n  = T >> 10;
    const int d  = ch & 63;
    const int hh = (ch >> 6) & 7;
    const float Aneg1 = NLOG2E * Ap[(hh * D_DIM + d) * N_DIM + n];

    const float* bp = bagg + n * 1024 + ch;
    float*       pq = pref + n * 1024 + ch;

    float p = 0.0f;
    for (int k = 0; k < NKC; k += 8) {
        float sd[8], bb[8];
#pragma unroll
        for (int i = 0; i < 8; ++i) {
            sd[i] = sdtb[(k + i) * 1024 + ch];
            bb[i] = bp[(size_t)(k + i) * 32768];
        }
#pragma unroll
        for (int i = 0; i < 8; ++i) {
            pq[(size_t)(k + i) * 32768] = p;
            const float a = __builtin_amdgcn_exp2f(Aneg1 * sd[i]);
            p = fmaf(a, p, bb[i]);
        }
    }
}

__global__ __launch_bounds__(256, 4) void ssm_k3(
    const float* __restrict__ dtp, const float* __restrict__ up,
    const float* __restrict__ Ap,  const float* __restrict__ Bp,
    const float* __restrict__ Cp,  const float* __restrict__ Dp,
    const float* __restrict__ pref, float* __restrict__ outp)
{
    const int tid  = threadIdx.x;
    const int w    = tid >> 6;
    const int lane = tid & 63;
    const int pp   = w >> 1;
    const int dh   = w & 1;
    const int dlow = lane & 31;
    const int nh   = lane >> 5;
    const int bh   = blockIdx.x >> 6;
    const int kcg  = blockIdx.x & 63;
    const int kc   = kcg * 2 + pp;
    const int b = bh >> 3, hh = bh & 7;
    const int d  = dh * 32 + dlow;
    const int n0 = nh * 16;
    const int ch = bh * 64 + d;

    float Aneg[16];
    {
        const float* Arow = Ap + (hh * D_DIM + d) * N_DIM + n0;
#pragma unroll
        for (int j = 0; j < 4; ++j) {
            float4 a4 = *(const float4*)(Arow + j * 4);
            Aneg[4*j+0] = NLOG2E * a4.x; Aneg[4*j+1] = NLOG2E * a4.y;
            Aneg[4*j+2] = NLOG2E * a4.z; Aneg[4*j+3] = NLOG2E * a4.w;
        }
    }

    float h[16];
    {
        const int pb = kc * 32768 + ch;
#pragma unroll
        for (int j = 0; j < 16; ++j) h[j] = pref[pb + (n0 + j) * 1024];
    }

    const float Dv = Dp[hh];
    const int base_ud = b * (S_LEN * 512) + hh * 64 + d;
    const int base_bc = b * (S_LEN * 256) + hh * 32 + n0;
    const int s0 = kc * TW;

#pragma unroll 4
    for (int t = 0; t < TW; ++t) {
        const int s = s0 + t;
        const float dtv = dtp[base_ud + s * 512];
        const float uv  = up [base_ud + s * 512];
        const float kk  = dtv * uv;
        const float4* B4 = reinterpret_cast<const float4*>(Bp + base_bc + s * 256);
        const float4* C4 = reinterpret_cast<const float4*>(Cp + base_bc + s * 256);
        float y0 = 0.0f, y1 = 0.0f, y2 = 0.0f, y3 = 0.0f;
#pragma unroll
        for (int j = 0; j < 4; ++j) {
            const float4 Bv = B4[j];
            const float4 Cv = C4[j];
#pragma unroll
            for (int q = 0; q < 4; ++q) {
                const int jn = j * 4 + q;
                const float bq = (q == 0) ? Bv.x : (q == 1) ? Bv.y : (q == 2) ? Bv.z : Bv.w;
                const float cq = (q == 0) ? Cv.x : (q == 1) ? Cv.y : (q == 2) ? Cv.z : Cv.w;
                const float e = __builtin_amdgcn_exp2f(dtv * Aneg[jn]);
                h[jn] = fmaf(e, h[jn], kk * bq);
                if (q == 0)      y0 = fmaf(h[jn], cq, y0);
                else if (q == 1) y1 = fmaf(h[jn], cq, y1);
                else if (q == 2) y2 = fmaf(h[jn], cq, y2);
                else             y3 = fmaf(h[jn], cq, y3);
            }
        }
        float y = (y0 + y1) + (y2 + y3);
        y += __shfl_xor(y, 32);
        if (nh == 0) outp[base_ud + s * 512] = fmaf(Dv, uv, y);
    }
}

} // namespace

extern "C" void kernel_launch(void* const* d_in, const int* in_sizes, int n_in,
                              void* d_out, int out_size, void* d_ws, size_t ws_size,
                              hipStream_t stream)
{
    const float* u  = (const float*)d_in[0];
    const float* dt = (const float*)d_in[1];
    const float* A  = (const float*)d_in[2];
    const float* B  = (const float*)d_in[3];
    const float* C  = (const float*)d_in[4];
    const float* D  = (const float*)d_in[5];
    float* out = (float*)d_out;

    float* sdtb = (float*)d_ws;                         // 128*1024       = 0.5 MB
    float* bagg = sdtb + (size_t)NKC * 1024;            // 128*32*1024    = 16.8 MB
    float* pref = bagg + (size_t)NKC * 32 * 1024;       // 128*32*1024    = 16.8 MB

    ssm_k1<<<dim3(16 * 64), dim3(256), 0, stream>>>(dt, u, A, B, sdtb, bagg);
    ssm_k2<<<dim3(128),     dim3(256), 0, stream>>>(sdtb, bagg, A, pref);
    ssm_k3<<<dim3(16 * 64), dim3(256), 0, stream>>>(dt, u, A, B, C, D, pref, out);
}

// Round 11
// 49.028 us; speedup vs baseline: 1.1774x; 1.1774x over previous
//
#include <hip/hip_runtime.h>

namespace {

constexpr int S_LEN = 2048;
constexpr int H_N   = 8;
constexpr int D_DIM = 64;
constexpr int N_DIM = 32;
constexpr int TW    = 16;             // timesteps per chunk
constexpr int NKC   = S_LEN / TW;     // 128 chunks per (b,h)
constexpr float NLOG2E = -1.4426950408889634f;

// ws:
//   sdtb: [kc][ch]      128*1024  (0.5 MB) — sum of dt over chunk
//   bagg: [kc][n][ch]   128*32*1024 (16.8 MB) — chunk b-aggregate
//   pref: [kc][n][ch]   128*32*1024 (16.8 MB) — state entering chunk
// Block = bh*64 + kcg, 256 thr = 4 waves = 2 wave-pairs; pair pp = w>>1 owns
// chunk kc = kcg*2+pp, dh = w&1. lane: dlow=lane&31, nh=lane>>5; d=dh*32+dlow;
// thread owns n in [nh*16, nh*16+16). No __syncthreads: dt/u prefetched to
// registers (half-wave 128B coalesced), B/C staged per-wave into private LDS.

__global__ __launch_bounds__(256, 4) void ssm_k1(
    const float* __restrict__ dtp, const float* __restrict__ up,
    const float* __restrict__ Ap,  const float* __restrict__ Bp,
    float* __restrict__ sdtb, float* __restrict__ bagg)
{
    __shared__ float lB[4][TW * 32];      // per-wave B slab (2 KB each)

    const int tid  = threadIdx.x;
    const int w    = tid >> 6;
    const int lane = tid & 63;
    const int pp   = w >> 1;
    const int dh   = w & 1;
    const int dlow = lane & 31;
    const int nh   = lane >> 5;
    const int bh   = blockIdx.x >> 6;
    const int kcg  = blockIdx.x & 63;
    const int kc   = kcg * 2 + pp;
    const int b = bh >> 3, hh = bh & 7;
    const int d  = dh * 32 + dlow;
    const int n0 = nh * 16;
    const int ch = bh * 64 + d;
    const int s0 = kc * TW;

    const int base_ud = b * (S_LEN * 512) + hh * 64 + d;
    const int bB      = b * (S_LEN * 256) + hh * 32 + s0 * 256;

    // ---- per-wave stage: B slab -> my LDS region ----
#pragma unroll
    for (int it = 0; it < 2; ++it) {
        const int idx = it * 64 + lane;           // 0..127 float4s
        const int row = idx >> 3, col = idx & 7;
        const float4 v = *(const float4*)(Bp + bB + row * 256 + col * 4);
        *(float4*)&lB[w][idx * 4] = v;
    }

    // ---- bulk prefetch dt/u into registers ----
    float dtv[TW], uv[TW];
#pragma unroll
    for (int t = 0; t < TW; ++t) {
        dtv[t] = dtp[base_ud + (s0 + t) * 512];
        uv[t]  = up [base_ud + (s0 + t) * 512];
    }

    float Aneg[16];
    {
        const float* Arow = Ap + (hh * D_DIM + d) * N_DIM + n0;
#pragma unroll
        for (int j = 0; j < 4; ++j) {
            float4 a4 = *(const float4*)(Arow + j * 4);
            Aneg[4*j+0] = NLOG2E * a4.x; Aneg[4*j+1] = NLOG2E * a4.y;
            Aneg[4*j+2] = NLOG2E * a4.z; Aneg[4*j+3] = NLOG2E * a4.w;
        }
    }

    float bA[16];
#pragma unroll
    for (int j = 0; j < 16; ++j) bA[j] = 0.0f;
    float sdt = 0.0f;

#pragma unroll 4
    for (int t = 0; t < TW; ++t) {
        const float kk = dtv[t] * uv[t];
        sdt += dtv[t];
#pragma unroll
        for (int j = 0; j < 4; ++j) {
            const float4 Bv = *(const float4*)&lB[w][t * 32 + n0 + j * 4];
#pragma unroll
            for (int q = 0; q < 4; ++q) {
                const int jn = j * 4 + q;
                const float bq = (q == 0) ? Bv.x : (q == 1) ? Bv.y : (q == 2) ? Bv.z : Bv.w;
                const float e = __builtin_amdgcn_exp2f(dtv[t] * Aneg[jn]);
                bA[jn] = fmaf(e, bA[jn], kk * bq);
            }
        }
    }

    if (nh == 0) sdtb[kc * 1024 + ch] = sdt;
    const int ab = kc * 32768 + ch;
#pragma unroll
    for (int j = 0; j < 16; ++j)
        bagg[ab + (n0 + j) * 1024] = bA[j];
}

__global__ __launch_bounds__(256) void ssm_k2(
    const float* __restrict__ sdtb, const float* __restrict__ bagg,
    const float* __restrict__ Ap,   float* __restrict__ pref)
{
    const int T  = blockIdx.x * 256 + threadIdx.x;   // 32768 threads = (n, ch)
    const int ch = T & 1023;
    const int n  = T >> 10;
    const int d  = ch & 63;
    const int hh = (ch >> 6) & 7;
    const float Aneg1 = NLOG2E * Ap[(hh * D_DIM + d) * N_DIM + n];

    const float* bp = bagg + n * 1024 + ch;
    float*       pq = pref + n * 1024 + ch;

    float p = 0.0f;
    for (int k = 0; k < NKC; k += 8) {
        float sd[8], bb[8];
#pragma unroll
        for (int i = 0; i < 8; ++i) {
            sd[i] = sdtb[(k + i) * 1024 + ch];
            bb[i] = bp[(size_t)(k + i) * 32768];
        }
#pragma unroll
        for (int i = 0; i < 8; ++i) {
            pq[(size_t)(k + i) * 32768] = p;
            const float a = __builtin_amdgcn_exp2f(Aneg1 * sd[i]);
            p = fmaf(a, p, bb[i]);
        }
    }
}

__global__ __launch_bounds__(256, 4) void ssm_k3(
    const float* __restrict__ dtp, const float* __restrict__ up,
    const float* __restrict__ Ap,  const float* __restrict__ Bp,
    const float* __restrict__ Cp,  const float* __restrict__ Dp,
    const float* __restrict__ pref, float* __restrict__ outp)
{
    __shared__ float lB[4][TW * 32];
    __shared__ float lC[4][TW * 32];

    const int tid  = threadIdx.x;
    const int w    = tid >> 6;
    const int lane = tid & 63;
    const int pp   = w >> 1;
    const int dh   = w & 1;
    const int dlow = lane & 31;
    const int nh   = lane >> 5;
    const int bh   = blockIdx.x >> 6;
    const int kcg  = blockIdx.x & 63;
    const int kc   = kcg * 2 + pp;
    const int b = bh >> 3, hh = bh & 7;
    const int d  = dh * 32 + dlow;
    const int n0 = nh * 16;
    const int ch = bh * 64 + d;
    const int s0 = kc * TW;

    const int base_ud = b * (S_LEN * 512) + hh * 64 + d;
    const int bB      = b * (S_LEN * 256) + hh * 32 + s0 * 256;

    // ---- per-wave stage: B and C slabs -> my LDS regions ----
#pragma unroll
    for (int it = 0; it < 2; ++it) {
        const int idx = it * 64 + lane;
        const int row = idx >> 3, col = idx & 7;
        const float4 vb = *(const float4*)(Bp + bB + row * 256 + col * 4);
        const float4 vc = *(const float4*)(Cp + bB + row * 256 + col * 4);
        *(float4*)&lB[w][idx * 4] = vb;
        *(float4*)&lC[w][idx * 4] = vc;
    }

    // ---- bulk prefetch dt/u + entering state h ----
    float dtv[TW], uv[TW];
#pragma unroll
    for (int t = 0; t < TW; ++t) {
        dtv[t] = dtp[base_ud + (s0 + t) * 512];
        uv[t]  = up [base_ud + (s0 + t) * 512];
    }

    float h[16];
    {
        const int pb = kc * 32768 + ch;
#pragma unroll
        for (int j = 0; j < 16; ++j) h[j] = pref[pb + (n0 + j) * 1024];
    }

    float Aneg[16];
    {
        const float* Arow = Ap + (hh * D_DIM + d) * N_DIM + n0;
#pragma unroll
        for (int j = 0; j < 4; ++j) {
            float4 a4 = *(const float4*)(Arow + j * 4);
            Aneg[4*j+0] = NLOG2E * a4.x; Aneg[4*j+1] = NLOG2E * a4.y;
            Aneg[4*j+2] = NLOG2E * a4.z; Aneg[4*j+3] = NLOG2E * a4.w;
        }
    }

    const float Dv = Dp[hh];

#pragma unroll 4
    for (int t = 0; t < TW; ++t) {
        const float kk = dtv[t] * uv[t];
        float y0 = 0.0f, y1 = 0.0f, y2 = 0.0f, y3 = 0.0f;
#pragma unroll
        for (int j = 0; j < 4; ++j) {
            const float4 Bv = *(const float4*)&lB[w][t * 32 + n0 + j * 4];
            const float4 Cv = *(const float4*)&lC[w][t * 32 + n0 + j * 4];
#pragma unroll
            for (int q = 0; q < 4; ++q) {
                const int jn = j * 4 + q;
                const float bq = (q == 0) ? Bv.x : (q == 1) ? Bv.y : (q == 2) ? Bv.z : Bv.w;
                const float cq = (q == 0) ? Cv.x : (q == 1) ? Cv.y : (q == 2) ? Cv.z : Cv.w;
                const float e = __builtin_amdgcn_exp2f(dtv[t] * Aneg[jn]);
                h[jn] = fmaf(e, h[jn], kk * bq);
                if (q == 0)      y0 = fmaf(h[jn], cq, y0);
                else if (q == 1) y1 = fmaf(h[jn], cq, y1);
                else if (q == 2) y2 = fmaf(h[jn], cq, y2);
                else             y3 = fmaf(h[jn], cq, y3);
            }
        }
        float y = (y0 + y1) + (y2 + y3);
        y += __shfl_xor(y, 32);
        if (nh == 0) outp[base_ud + (s0 + t) * 512] = fmaf(Dv, uv[t], y);
    }
}

} // namespace

extern "C" void kernel_launch(void* const* d_in, const int* in_sizes, int n_in,
                              void* d_out, int out_size, void* d_ws, size_t ws_size,
                              hipStream_t stream)
{
    const float* u  = (const float*)d_in[0];
    const float* dt = (const float*)d_in[1];
    const float* A  = (const float*)d_in[2];
    const float* B  = (const float*)d_in[3];
    const float* C  = (const float*)d_in[4];
    const float* D  = (const float*)d_in[5];
    float* out = (float*)d_out;

    float* sdtb = (float*)d_ws;                         // 0.5 MB
    float* bagg = sdtb + (size_t)NKC * 1024;            // 16.8 MB
    float* pref = bagg + (size_t)NKC * 32 * 1024;       // 16.8 MB

    ssm_k1<<<dim3(16 * 64), dim3(256), 0, stream>>>(dt, u, A, B, sdtb, bagg);
    ssm_k2<<<dim3(128),     dim3(256), 0, stream>>>(sdtb, bagg, A, pref);
    ssm_k3<<<dim3(16 * 64), dim3(256), 0, stream>>>(dt, u, A, B, C, D, pref, out);
}